// Round 6
// baseline (376.531 us; speedup 1.0000x reference)
//
#include <hip/hip_runtime.h>
#include <math.h>

#define B_   8
#define N_   16384
#define M_   64
#define C_   192
#define RC_  16
#define ROWS 128   // rows per main block (512 threads, 8 waves)

#define FMA4(acc, s, v) \
    acc.x = fmaf(s, v.x, acc.x); acc.y = fmaf(s, v.y, acc.y); \
    acc.z = fmaf(s, v.z, acc.z); acc.w = fmaf(s, v.w, acc.w)

// ---------------------------------------------------------------------------
// K_prep: fused  v = dict@wv+b  ->  depthwise conv3x1 + GELU  -> ws_vg
//         and    k = l2norm(LN(dict@wk+b))                    -> ws_k
// (unchanged — verified correct)
// ---------------------------------------------------------------------------
__global__ __launch_bounds__(256) void k_prep_kernel(
    const float* __restrict__ dict,
    const float* __restrict__ wv_w, const float* __restrict__ wv_b,
    const float* __restrict__ conv_w, const float* __restrict__ conv_b,
    const float* __restrict__ wk_w, const float* __restrict__ wk_b,
    const float* __restrict__ kn_g, const float* __restrict__ kn_b,
    float* __restrict__ ws_vg, float* __restrict__ ws_k)
{
    const int b   = blockIdx.x >> 6;
    const int m   = blockIdx.x & 63;
    const int tid = threadIdx.x;
    const float* d0 = dict + (b * M_ + m) * C_;

    if (tid < 192) {
        const int c = tid;
        const bool hm = (m > 0), hp = (m < M_ - 1);
        const float* dm = hm ? d0 - C_ : d0;
        const float* dp = hp ? d0 + C_ : d0;
        float am = 0.f, ac = 0.f, ap = 0.f;
        #pragma unroll 4
        for (int d = 0; d < C_; ++d) {
            const float w = wv_w[d * C_ + c];
            am = fmaf(dm[d], w, am);
            ac = fmaf(d0[d], w, ac);
            ap = fmaf(dp[d], w, ap);
        }
        const float bia = wv_b[c];
        const float up = hm ? (am + bia) : 0.f;
        const float ct = ac + bia;
        const float dn = hp ? (ap + bia) : 0.f;
        float t = conv_b[c];
        t = fmaf(up, conv_w[c*9 + 1], t);
        t = fmaf(ct, conv_w[c*9 + 4], t);
        t = fmaf(dn, conv_w[c*9 + 7], t);
        ws_vg[(b * M_ + m) * C_ + c] = 0.5f * t * (1.0f + erff(t * 0.70710678118654752f));
    } else if (tid < 196) {
        const int j4 = tid - 192;
        const int c0 = j4 * 4;
        float a0 = wk_b[c0+0], a1 = wk_b[c0+1], a2 = wk_b[c0+2], a3 = wk_b[c0+3];
        #pragma unroll 4
        for (int d4 = 0; d4 < C_/4; ++d4) {
            const float4 xv = ((const float4*)d0)[d4];
            const float4 w0 = *(const float4*)&wk_w[(d4*4+0)*RC_ + c0];
            const float4 w1 = *(const float4*)&wk_w[(d4*4+1)*RC_ + c0];
            const float4 w2 = *(const float4*)&wk_w[(d4*4+2)*RC_ + c0];
            const float4 w3 = *(const float4*)&wk_w[(d4*4+3)*RC_ + c0];
            a0 = fmaf(xv.x, w0.x, a0); a1 = fmaf(xv.x, w0.y, a1); a2 = fmaf(xv.x, w0.z, a2); a3 = fmaf(xv.x, w0.w, a3);
            a0 = fmaf(xv.y, w1.x, a0); a1 = fmaf(xv.y, w1.y, a1); a2 = fmaf(xv.y, w1.z, a2); a3 = fmaf(xv.y, w1.w, a3);
            a0 = fmaf(xv.z, w2.x, a0); a1 = fmaf(xv.z, w2.y, a1); a2 = fmaf(xv.z, w2.z, a2); a3 = fmaf(xv.z, w2.w, a3);
            a0 = fmaf(xv.w, w3.x, a0); a1 = fmaf(xv.w, w3.y, a1); a2 = fmaf(xv.w, w3.z, a2); a3 = fmaf(xv.w, w3.w, a3);
        }
        float s  = a0 + a1 + a2 + a3;
        float ss = a0*a0 + a1*a1 + a2*a2 + a3*a3;
        s  += __shfl_xor(s, 1);  s  += __shfl_xor(s, 2);
        ss += __shfl_xor(ss, 1); ss += __shfl_xor(ss, 2);
        const float mu   = s * (1.0f/16.0f);
        const float var  = ss * (1.0f/16.0f) - mu*mu;
        const float rstd = rsqrtf(var + 1e-5f);
        const float4 g4 = *(const float4*)&kn_g[c0];
        const float4 b4 = *(const float4*)&kn_b[c0];
        const float y0 = (a0 - mu) * rstd * g4.x + b4.x;
        const float y1 = (a1 - mu) * rstd * g4.y + b4.y;
        const float y2 = (a2 - mu) * rstd * g4.z + b4.z;
        const float y3 = (a3 - mu) * rstd * g4.w + b4.w;
        float n2 = y0*y0 + y1*y1 + y2*y2 + y3*y3;
        n2 += __shfl_xor(n2, 1); n2 += __shfl_xor(n2, 2);
        const float inv = 1.0f / fmaxf(sqrtf(n2), 1e-12f);
        float4 o; o.x = y0*inv; o.y = y1*inv; o.z = y2*inv; o.w = y3*inv;
        *(float4*)&ws_k[(b * M_ + m) * RC_ + c0] = o;
    }
}

// ---------------------------------------------------------------------------
// K_main: 512 threads, 128 rows/block, LDS 52 KB -> 2 blocks/CU = 16 waves.
//   __launch_bounds__(512, 2): VGPR cap 128, no spills (r4's forced-4 spilled).
//   (a) q proj + LN + l2norm   thread (r=tid>>2, j4); quad shfl stats
//   (b) softmax                thread (r,j4) owns m = 4*mm+j4; sc in regs
//   (c) out = attn @ vg        lane (rql=l>>4, cq=l&15): 4 rows x 12 ch tile.
//       DS pipe per wave per m: 3 ds_read_b128 + 4 bperm ~ 59 cyc
//       (vs 150 for row-owned mapping -> DS-pipe time/CU 128 -> ~50 us).
// ---------------------------------------------------------------------------
__global__ __launch_bounds__(512, 2) void k_main_kernel(
    const float* __restrict__ x, const float* __restrict__ ws_k,
    const float* __restrict__ ws_vg,
    const float* __restrict__ wq_w, const float* __restrict__ wq_b,
    const float* __restrict__ qn_g, const float* __restrict__ qn_b,
    const float* __restrict__ temp,
    float* __restrict__ out, float* __restrict__ attn_out)
{
    __shared__ float vg_s[M_ * C_];   // 48 KB
    __shared__ float k_s[M_ * RC_];   // 4 KB

    const int tid   = threadIdx.x;
    const int b     = blockIdx.x >> 7;
    const int n0    = (blockIdx.x & 127) * ROWS;
    const int lane  = tid & 63;
    const int lbase = lane & ~3;

    // ---- T14 stage-issue: global->regs now; LDS write after phase (a) ----
    float4 st[6]; float4 kst;
    {
        const float4* vgb4 = (const float4*)(ws_vg + b * (M_ * C_));
        #pragma unroll
        for (int i = 0; i < 6; ++i) st[i] = vgb4[tid + 512 * i];
        if (tid < 256) kst = ((const float4*)(ws_k + b * (M_ * RC_)))[tid];
    }

    const int r  = tid >> 2;      // 0..127
    const int j4 = tid & 3;
    const int c0 = j4 * 4;

    // ---- phase (a): q projection + LN + l2norm (hides staging latency) ----
    const float* xr = x + (size_t)(b * N_ + n0 + r) * C_;
    float a0 = wq_b[c0+0], a1 = wq_b[c0+1], a2 = wq_b[c0+2], a3 = wq_b[c0+3];
    #pragma unroll 4
    for (int d4 = 0; d4 < C_/4; ++d4) {
        const float4 xv = ((const float4*)xr)[d4];
        const float4 w0 = *(const float4*)&wq_w[(d4*4+0)*RC_ + c0];
        const float4 w1 = *(const float4*)&wq_w[(d4*4+1)*RC_ + c0];
        const float4 w2 = *(const float4*)&wq_w[(d4*4+2)*RC_ + c0];
        const float4 w3 = *(const float4*)&wq_w[(d4*4+3)*RC_ + c0];
        a0 = fmaf(xv.x, w0.x, a0); a1 = fmaf(xv.x, w0.y, a1); a2 = fmaf(xv.x, w0.z, a2); a3 = fmaf(xv.x, w0.w, a3);
        a0 = fmaf(xv.y, w1.x, a0); a1 = fmaf(xv.y, w1.y, a1); a2 = fmaf(xv.y, w1.z, a2); a3 = fmaf(xv.y, w1.w, a3);
        a0 = fmaf(xv.z, w2.x, a0); a1 = fmaf(xv.z, w2.y, a1); a2 = fmaf(xv.z, w2.z, a2); a3 = fmaf(xv.z, w2.w, a3);
        a0 = fmaf(xv.w, w3.x, a0); a1 = fmaf(xv.w, w3.y, a1); a2 = fmaf(xv.w, w3.z, a2); a3 = fmaf(xv.w, w3.w, a3);
    }
    float4 q[4];
    {
        float s  = a0 + a1 + a2 + a3;
        float ss = a0*a0 + a1*a1 + a2*a2 + a3*a3;
        s  += __shfl_xor(s, 1);  s  += __shfl_xor(s, 2);
        ss += __shfl_xor(ss, 1); ss += __shfl_xor(ss, 2);
        const float mu   = s * (1.0f/16.0f);
        const float var  = ss * (1.0f/16.0f) - mu*mu;
        const float rstd = rsqrtf(var + 1e-5f);
        const float4 g4 = *(const float4*)&qn_g[c0];
        const float4 b4 = *(const float4*)&qn_b[c0];
        const float y0 = (a0 - mu) * rstd * g4.x + b4.x;
        const float y1 = (a1 - mu) * rstd * g4.y + b4.y;
        const float y2 = (a2 - mu) * rstd * g4.z + b4.z;
        const float y3 = (a3 - mu) * rstd * g4.w + b4.w;
        float n2 = y0*y0 + y1*y1 + y2*y2 + y3*y3;
        n2 += __shfl_xor(n2, 1); n2 += __shfl_xor(n2, 2);
        const float inv = 1.0f / fmaxf(sqrtf(n2), 1e-12f);
        float4 o; o.x = y0*inv; o.y = y1*inv; o.z = y2*inv; o.w = y3*inv;
        #pragma unroll
        for (int j = 0; j < 4; ++j) {
            q[j].x = __shfl(o.x, lbase + j);
            q[j].y = __shfl(o.y, lbase + j);
            q[j].z = __shfl(o.z, lbase + j);
            q[j].w = __shfl(o.w, lbase + j);
        }
    }
    const float tinv = 1.0f / fmaxf(temp[0], 0.5f);

    // ---- stage-write: regs -> LDS, single barrier ----
    {
        #pragma unroll
        for (int i = 0; i < 6; ++i) ((float4*)vg_s)[tid + 512 * i] = st[i];
        if (tid < 256) ((float4*)k_s)[tid] = kst;
    }
    __syncthreads();

    // ---- phase (b): scores + softmax; thread owns m = 4*mm + j4 ----
    float sc[16];
    {
        #pragma unroll
        for (int mm = 0; mm < 16; ++mm) {
            const int m = mm*4 + j4;
            const float4 k0 = *(const float4*)&k_s[m*RC_ + 0];
            const float4 k1 = *(const float4*)&k_s[m*RC_ + 4];
            const float4 k2 = *(const float4*)&k_s[m*RC_ + 8];
            const float4 k3 = *(const float4*)&k_s[m*RC_ + 12];
            float d = q[0].x*k0.x;
            d = fmaf(q[0].y, k0.y, d); d = fmaf(q[0].z, k0.z, d); d = fmaf(q[0].w, k0.w, d);
            d = fmaf(q[1].x, k1.x, d); d = fmaf(q[1].y, k1.y, d); d = fmaf(q[1].z, k1.z, d); d = fmaf(q[1].w, k1.w, d);
            d = fmaf(q[2].x, k2.x, d); d = fmaf(q[2].y, k2.y, d); d = fmaf(q[2].z, k2.z, d); d = fmaf(q[2].w, k2.w, d);
            d = fmaf(q[3].x, k3.x, d); d = fmaf(q[3].y, k3.y, d); d = fmaf(q[3].z, k3.z, d); d = fmaf(q[3].w, k3.w, d);
            sc[mm] = d * tinv;
        }
        float mx = sc[0];
        #pragma unroll
        for (int mm = 1; mm < 16; ++mm) mx = fmaxf(mx, sc[mm]);
        mx = fmaxf(mx, __shfl_xor(mx, 1)); mx = fmaxf(mx, __shfl_xor(mx, 2));
        float es = 0.0f;
        #pragma unroll
        for (int mm = 0; mm < 16; ++mm) { sc[mm] = expf(sc[mm] - mx); es += sc[mm]; }
        es += __shfl_xor(es, 1); es += __shfl_xor(es, 2);
        const float einv = 1.0f / es;
        float* aw = attn_out + (size_t)(b * N_ + n0 + r) * M_;
        #pragma unroll
        for (int mm = 0; mm < 16; ++mm) {
            sc[mm] *= einv;                 // normalized attn stays in regs
            aw[mm*4 + j4] = sc[mm];
        }
    }
    // NO second barrier: attn exchange is intra-wave from here on.

    // ---- phase (c): out = attn @ vg; lane (rql,cq) = 4 rows x 12 channels.
    //      Row (16*wv + 4*rql + i): attn[.][m] owned by in-wave lane
    //      16*rql + 4*i + (m&3) at static index sc[m>>2] -> 4 shfl per m.
    //      vg: 3 ds_read_b128 per m (lanes stride 48 B -> worst 2-way = free). ----
    {
        const int w0lane = tid & 63;
        const int rql = w0lane >> 4;            // 0..3
        const int cq  = w0lane & 15;            // 0..15
        const int wv  = tid >> 6;               // wave id
        const int bl  = rql * 16;               // owner-lane base (i adds 4i)

        float4 ac0[3], ac1[3], ac2[3], ac3[3];
        #pragma unroll
        for (int t = 0; t < 3; ++t) {
            ac0[t] = make_float4(0.f,0.f,0.f,0.f);
            ac1[t] = make_float4(0.f,0.f,0.f,0.f);
            ac2[t] = make_float4(0.f,0.f,0.f,0.f);
            ac3[t] = make_float4(0.f,0.f,0.f,0.f);
        }
        #pragma unroll
        for (int m = 0; m < M_; ++m) {
            const float p0 = __shfl(sc[m >> 2], bl + 0  + (m & 3));
            const float p1 = __shfl(sc[m >> 2], bl + 4  + (m & 3));
            const float p2 = __shfl(sc[m >> 2], bl + 8  + (m & 3));
            const float p3 = __shfl(sc[m >> 2], bl + 12 + (m & 3));
            const float4* vr = (const float4*)(vg_s + m*C_ + cq*12);
            #pragma unroll
            for (int t = 0; t < 3; ++t) {
                const float4 v = vr[t];
                FMA4(ac0[t], p0, v);
                FMA4(ac1[t], p1, v);
                FMA4(ac2[t], p2, v);
                FMA4(ac3[t], p3, v);
            }
        }
        const int row0 = 16*wv + 4*rql;
        float* o0 = out + (size_t)(b * N_ + n0 + row0) * C_ + cq*12;
        #pragma unroll
        for (int t = 0; t < 3; ++t) {
            *(float4*)&o0[t*4]          = ac0[t];
            *(float4*)&o0[C_   + t*4]   = ac1[t];
            *(float4*)&o0[2*C_ + t*4]   = ac2[t];
            *(float4*)&o0[3*C_ + t*4]   = ac3[t];
        }
    }
}

// ---------------------------------------------------------------------------
extern "C" void kernel_launch(void* const* d_in, const int* in_sizes, int n_in,
                              void* d_out, int out_size, void* d_ws, size_t ws_size,
                              hipStream_t stream) {
    const float* x      = (const float*)d_in[0];
    const float* dict   = (const float*)d_in[1];
    const float* wq_w   = (const float*)d_in[4];
    const float* wq_b   = (const float*)d_in[5];
    const float* wk_w   = (const float*)d_in[6];
    const float* wk_b   = (const float*)d_in[7];
    const float* wv_w   = (const float*)d_in[8];
    const float* wv_b   = (const float*)d_in[9];
    const float* qn_g   = (const float*)d_in[10];
    const float* qn_b   = (const float*)d_in[11];
    const float* kn_g   = (const float*)d_in[12];
    const float* kn_b   = (const float*)d_in[13];
    const float* conv_w = (const float*)d_in[14];
    const float* conv_b = (const float*)d_in[15];
    const float* temp   = (const float*)d_in[16];

    float* out  = (float*)d_out;                          // (B,N,192)
    float* attn = out + (size_t)B_ * N_ * C_;             // (B,N,64)

    float* ws_vg = (float*)d_ws;                          // B*M*C = 98304 f
    float* ws_k  = ws_vg + B_ * M_ * C_;                  // 8192 f

    k_prep_kernel<<<B_ * M_,          256, 0, stream>>>(dict, wv_w, wv_b, conv_w, conv_b,
                                                        wk_w, wk_b, kn_g, kn_b, ws_vg, ws_k);
    k_main_kernel<<<B_ * (N_ / ROWS), 512, 0, stream>>>(x, ws_k, ws_vg, wq_w, wq_b,
                                                        qn_g, qn_b, temp, out, attn);
}

// Round 7
// 346.559 us; speedup vs baseline: 1.0865x; 1.0865x over previous
//
#include <hip/hip_runtime.h>
#include <math.h>

#define B_   8
#define N_   16384
#define M_   64
#define C_   192
#define RC_  16

#define FMA4(acc, s, v) \
    acc.x = fmaf(s, v.x, acc.x); acc.y = fmaf(s, v.y, acc.y); \
    acc.z = fmaf(s, v.z, acc.z); acc.w = fmaf(s, v.w, acc.w)

// ---------------------------------------------------------------------------
// K_prep: fused  v = dict@wv+b  ->  depthwise conv3x1 + GELU  -> ws_vg
//         and    k = l2norm(LN(dict@wk+b))                    -> ws_k
// (unchanged — verified correct)
// ---------------------------------------------------------------------------
__global__ __launch_bounds__(256) void k_prep_kernel(
    const float* __restrict__ dict,
    const float* __restrict__ wv_w, const float* __restrict__ wv_b,
    const float* __restrict__ conv_w, const float* __restrict__ conv_b,
    const float* __restrict__ wk_w, const float* __restrict__ wk_b,
    const float* __restrict__ kn_g, const float* __restrict__ kn_b,
    float* __restrict__ ws_vg, float* __restrict__ ws_k)
{
    const int b   = blockIdx.x >> 6;
    const int m   = blockIdx.x & 63;
    const int tid = threadIdx.x;
    const float* d0 = dict + (b * M_ + m) * C_;

    if (tid < 192) {
        const int c = tid;
        const bool hm = (m > 0), hp = (m < M_ - 1);
        const float* dm = hm ? d0 - C_ : d0;
        const float* dp = hp ? d0 + C_ : d0;
        float am = 0.f, ac = 0.f, ap = 0.f;
        #pragma unroll 4
        for (int d = 0; d < C_; ++d) {
            const float w = wv_w[d * C_ + c];
            am = fmaf(dm[d], w, am);
            ac = fmaf(d0[d], w, ac);
            ap = fmaf(dp[d], w, ap);
        }
        const float bia = wv_b[c];
        const float up = hm ? (am + bia) : 0.f;
        const float ct = ac + bia;
        const float dn = hp ? (ap + bia) : 0.f;
        float t = conv_b[c];
        t = fmaf(up, conv_w[c*9 + 1], t);
        t = fmaf(ct, conv_w[c*9 + 4], t);
        t = fmaf(dn, conv_w[c*9 + 7], t);
        ws_vg[(b * M_ + m) * C_ + c] = 0.5f * t * (1.0f + erff(t * 0.70710678118654752f));
    } else if (tid < 196) {
        const int j4 = tid - 192;
        const int c0 = j4 * 4;
        float a0 = wk_b[c0+0], a1 = wk_b[c0+1], a2 = wk_b[c0+2], a3 = wk_b[c0+3];
        #pragma unroll 4
        for (int d4 = 0; d4 < C_/4; ++d4) {
            const float4 xv = ((const float4*)d0)[d4];
            const float4 w0 = *(const float4*)&wk_w[(d4*4+0)*RC_ + c0];
            const float4 w1 = *(const float4*)&wk_w[(d4*4+1)*RC_ + c0];
            const float4 w2 = *(const float4*)&wk_w[(d4*4+2)*RC_ + c0];
            const float4 w3 = *(const float4*)&wk_w[(d4*4+3)*RC_ + c0];
            a0 = fmaf(xv.x, w0.x, a0); a1 = fmaf(xv.x, w0.y, a1); a2 = fmaf(xv.x, w0.z, a2); a3 = fmaf(xv.x, w0.w, a3);
            a0 = fmaf(xv.y, w1.x, a0); a1 = fmaf(xv.y, w1.y, a1); a2 = fmaf(xv.y, w1.z, a2); a3 = fmaf(xv.y, w1.w, a3);
            a0 = fmaf(xv.z, w2.x, a0); a1 = fmaf(xv.z, w2.y, a1); a2 = fmaf(xv.z, w2.z, a2); a3 = fmaf(xv.z, w2.w, a3);
            a0 = fmaf(xv.w, w3.x, a0); a1 = fmaf(xv.w, w3.y, a1); a2 = fmaf(xv.w, w3.z, a2); a3 = fmaf(xv.w, w3.w, a3);
        }
        float s  = a0 + a1 + a2 + a3;
        float ss = a0*a0 + a1*a1 + a2*a2 + a3*a3;
        s  += __shfl_xor(s, 1);  s  += __shfl_xor(s, 2);
        ss += __shfl_xor(ss, 1); ss += __shfl_xor(ss, 2);
        const float mu   = s * (1.0f/16.0f);
        const float var  = ss * (1.0f/16.0f) - mu*mu;
        const float rstd = rsqrtf(var + 1e-5f);
        const float4 g4 = *(const float4*)&kn_g[c0];
        const float4 b4 = *(const float4*)&kn_b[c0];
        const float y0 = (a0 - mu) * rstd * g4.x + b4.x;
        const float y1 = (a1 - mu) * rstd * g4.y + b4.y;
        const float y2 = (a2 - mu) * rstd * g4.z + b4.z;
        const float y3 = (a3 - mu) * rstd * g4.w + b4.w;
        float n2 = y0*y0 + y1*y1 + y2*y2 + y3*y3;
        n2 += __shfl_xor(n2, 1); n2 += __shfl_xor(n2, 2);
        const float inv = 1.0f / fmaxf(sqrtf(n2), 1e-12f);
        float4 o; o.x = y0*inv; o.y = y1*inv; o.z = y2*inv; o.w = y3*inv;
        *(float4*)&ws_k[(b * M_ + m) * RC_ + c0] = o;
    }
}

// ---------------------------------------------------------------------------
// K_main: 256 threads (4 waves), 64 rows/block, grid 2048.
//   LDS = vg(48K)+k(4K) = 52K -> 3 blocks/CU = 12 waves/CU (r3 was 2 blk/8 w).
//   __launch_bounds__(256,3): 3 blocks/CU intent; VGPR cap ~680 -> no spills.
//   (a) q proj + LN + l2norm   thread (r=tid>>2, j4); quad shfl stats
//   (b) softmax                thread (r,j4) owns m = 4*mm+j4 (conflict-free
//       k_s reads); normalized attn stays in sc[16] regs; scalar attn stores
//   (c) out = attn @ vg        lane (rql,cq) = 4 rows x 12 ch tile;
//       attn[16wv+4rql+i][m] pulled in-wave from lane 16rql+4i+(m&3) at
//       static sc[m>>2] -> 4 shfl + 3 ds_read_b128 per m per wave (~60 cyc,
//       vs 150 row-owned r5, 48+attn_t-LDS r3). ONE barrier in the kernel.
// ---------------------------------------------------------------------------
__global__ __launch_bounds__(256, 3) void k_main_kernel(
    const float* __restrict__ x, const float* __restrict__ ws_k,
    const float* __restrict__ ws_vg,
    const float* __restrict__ wq_w, const float* __restrict__ wq_b,
    const float* __restrict__ qn_g, const float* __restrict__ qn_b,
    const float* __restrict__ temp,
    float* __restrict__ out, float* __restrict__ attn_out)
{
    __shared__ float vg_s[M_ * C_];   // 48 KB
    __shared__ float k_s[M_ * RC_];   // 4 KB

    const int tid   = threadIdx.x;
    const int b     = blockIdx.x >> 8;
    const int n0    = (blockIdx.x & 255) * M_;
    const int lane  = tid & 63;
    const int lbase = lane & ~3;

    // ---- T14 stage-issue: global->regs now; LDS write after phase (a) ----
    float4 st[12]; float4 kst;
    {
        const float4* vgb4 = (const float4*)(ws_vg + b * (M_ * C_));
        #pragma unroll
        for (int i = 0; i < 12; ++i) st[i] = vgb4[tid + 256 * i];
        kst = ((const float4*)(ws_k + b * (M_ * RC_)))[tid];
    }

    const int r  = tid >> 2;      // 0..63
    const int j4 = tid & 3;
    const int c0 = j4 * 4;

    // ---- phase (a): q projection + LN + l2norm (hides staging latency) ----
    const float* xr = x + (size_t)(b * N_ + n0 + r) * C_;
    float a0 = wq_b[c0+0], a1 = wq_b[c0+1], a2 = wq_b[c0+2], a3 = wq_b[c0+3];
    #pragma unroll 4
    for (int d4 = 0; d4 < C_/4; ++d4) {
        const float4 xv = ((const float4*)xr)[d4];
        const float4 w0 = *(const float4*)&wq_w[(d4*4+0)*RC_ + c0];
        const float4 w1 = *(const float4*)&wq_w[(d4*4+1)*RC_ + c0];
        const float4 w2 = *(const float4*)&wq_w[(d4*4+2)*RC_ + c0];
        const float4 w3 = *(const float4*)&wq_w[(d4*4+3)*RC_ + c0];
        a0 = fmaf(xv.x, w0.x, a0); a1 = fmaf(xv.x, w0.y, a1); a2 = fmaf(xv.x, w0.z, a2); a3 = fmaf(xv.x, w0.w, a3);
        a0 = fmaf(xv.y, w1.x, a0); a1 = fmaf(xv.y, w1.y, a1); a2 = fmaf(xv.y, w1.z, a2); a3 = fmaf(xv.y, w1.w, a3);
        a0 = fmaf(xv.z, w2.x, a0); a1 = fmaf(xv.z, w2.y, a1); a2 = fmaf(xv.z, w2.z, a2); a3 = fmaf(xv.z, w2.w, a3);
        a0 = fmaf(xv.w, w3.x, a0); a1 = fmaf(xv.w, w3.y, a1); a2 = fmaf(xv.w, w3.z, a2); a3 = fmaf(xv.w, w3.w, a3);
    }
    float4 q[4];
    {
        float s  = a0 + a1 + a2 + a3;
        float ss = a0*a0 + a1*a1 + a2*a2 + a3*a3;
        s  += __shfl_xor(s, 1);  s  += __shfl_xor(s, 2);
        ss += __shfl_xor(ss, 1); ss += __shfl_xor(ss, 2);
        const float mu   = s * (1.0f/16.0f);
        const float var  = ss * (1.0f/16.0f) - mu*mu;
        const float rstd = rsqrtf(var + 1e-5f);
        const float4 g4 = *(const float4*)&qn_g[c0];
        const float4 b4 = *(const float4*)&qn_b[c0];
        const float y0 = (a0 - mu) * rstd * g4.x + b4.x;
        const float y1 = (a1 - mu) * rstd * g4.y + b4.y;
        const float y2 = (a2 - mu) * rstd * g4.z + b4.z;
        const float y3 = (a3 - mu) * rstd * g4.w + b4.w;
        float n2 = y0*y0 + y1*y1 + y2*y2 + y3*y3;
        n2 += __shfl_xor(n2, 1); n2 += __shfl_xor(n2, 2);
        const float inv = 1.0f / fmaxf(sqrtf(n2), 1e-12f);
        float4 o; o.x = y0*inv; o.y = y1*inv; o.z = y2*inv; o.w = y3*inv;
        #pragma unroll
        for (int j = 0; j < 4; ++j) {
            q[j].x = __shfl(o.x, lbase + j);
            q[j].y = __shfl(o.y, lbase + j);
            q[j].z = __shfl(o.z, lbase + j);
            q[j].w = __shfl(o.w, lbase + j);
        }
    }
    const float tinv = 1.0f / fmaxf(temp[0], 0.5f);

    // ---- stage-write: regs -> LDS, single barrier ----
    {
        #pragma unroll
        for (int i = 0; i < 12; ++i) ((float4*)vg_s)[tid + 256 * i] = st[i];
        ((float4*)k_s)[tid] = kst;
    }
    __syncthreads();

    // ---- phase (b): scores + softmax; thread owns m = 4*mm + j4 ----
    float sc[16];
    {
        #pragma unroll
        for (int mm = 0; mm < 16; ++mm) {
            const int m = mm*4 + j4;
            const float4 k0 = *(const float4*)&k_s[m*RC_ + 0];
            const float4 k1 = *(const float4*)&k_s[m*RC_ + 4];
            const float4 k2 = *(const float4*)&k_s[m*RC_ + 8];
            const float4 k3 = *(const float4*)&k_s[m*RC_ + 12];
            float d = q[0].x*k0.x;
            d = fmaf(q[0].y, k0.y, d); d = fmaf(q[0].z, k0.z, d); d = fmaf(q[0].w, k0.w, d);
            d = fmaf(q[1].x, k1.x, d); d = fmaf(q[1].y, k1.y, d); d = fmaf(q[1].z, k1.z, d); d = fmaf(q[1].w, k1.w, d);
            d = fmaf(q[2].x, k2.x, d); d = fmaf(q[2].y, k2.y, d); d = fmaf(q[2].z, k2.z, d); d = fmaf(q[2].w, k2.w, d);
            d = fmaf(q[3].x, k3.x, d); d = fmaf(q[3].y, k3.y, d); d = fmaf(q[3].z, k3.z, d); d = fmaf(q[3].w, k3.w, d);
            sc[mm] = d * tinv;
        }
        float mx = sc[0];
        #pragma unroll
        for (int mm = 1; mm < 16; ++mm) mx = fmaxf(mx, sc[mm]);
        mx = fmaxf(mx, __shfl_xor(mx, 1)); mx = fmaxf(mx, __shfl_xor(mx, 2));
        float es = 0.0f;
        #pragma unroll
        for (int mm = 0; mm < 16; ++mm) { sc[mm] = expf(sc[mm] - mx); es += sc[mm]; }
        es += __shfl_xor(es, 1); es += __shfl_xor(es, 2);
        const float einv = 1.0f / es;
        float* aw = attn_out + (size_t)(b * N_ + n0 + r) * M_;
        #pragma unroll
        for (int mm = 0; mm < 16; ++mm) {
            sc[mm] *= einv;                 // normalized attn stays in regs
            aw[mm*4 + j4] = sc[mm];
        }
    }
    // NO second barrier: attn exchange is intra-wave from here on.

    // ---- phase (c): out = attn @ vg; lane (rql,cq) = 4 rows x 12 channels.
    //      Row (16*wv + 4*rql + i): attn[.][m] owned by in-wave lane
    //      16*rql + 4*i + (m&3), static index sc[m>>2] -> 4 shfl per m.
    //      vg: 3 ds_read_b128/m (lane stride 48B -> 2-way max = free). ----
    {
        const int w0lane = tid & 63;
        const int rql = w0lane >> 4;            // 0..3
        const int cq  = w0lane & 15;            // 0..15
        const int wv  = tid >> 6;               // wave id 0..3
        const int bl  = rql * 16;               // owner-lane base (i adds 4i)

        float4 ac0[3], ac1[3], ac2[3], ac3[3];
        #pragma unroll
        for (int t = 0; t < 3; ++t) {
            ac0[t] = make_float4(0.f,0.f,0.f,0.f);
            ac1[t] = make_float4(0.f,0.f,0.f,0.f);
            ac2[t] = make_float4(0.f,0.f,0.f,0.f);
            ac3[t] = make_float4(0.f,0.f,0.f,0.f);
        }
        #pragma unroll
        for (int m = 0; m < M_; ++m) {
            const float p0 = __shfl(sc[m >> 2], bl + 0  + (m & 3));
            const float p1 = __shfl(sc[m >> 2], bl + 4  + (m & 3));
            const float p2 = __shfl(sc[m >> 2], bl + 8  + (m & 3));
            const float p3 = __shfl(sc[m >> 2], bl + 12 + (m & 3));
            const float4* vr = (const float4*)(vg_s + m*C_ + cq*12);
            #pragma unroll
            for (int t = 0; t < 3; ++t) {
                const float4 v = vr[t];
                FMA4(ac0[t], p0, v);
                FMA4(ac1[t], p1, v);
                FMA4(ac2[t], p2, v);
                FMA4(ac3[t], p3, v);
            }
        }
        const int row0 = 16*wv + 4*rql;
        float* o0 = out + (size_t)(b * N_ + n0 + row0) * C_ + cq*12;
        #pragma unroll
        for (int t = 0; t < 3; ++t) {
            *(float4*)&o0[t*4]          = ac0[t];
            *(float4*)&o0[C_   + t*4]   = ac1[t];
            *(float4*)&o0[2*C_ + t*4]   = ac2[t];
            *(float4*)&o0[3*C_ + t*4]   = ac3[t];
        }
    }
}

// ---------------------------------------------------------------------------
extern "C" void kernel_launch(void* const* d_in, const int* in_sizes, int n_in,
                              void* d_out, int out_size, void* d_ws, size_t ws_size,
                              hipStream_t stream) {
    const float* x      = (const float*)d_in[0];
    const float* dict   = (const float*)d_in[1];
    const float* wq_w   = (const float*)d_in[4];
    const float* wq_b   = (const float*)d_in[5];
    const float* wk_w   = (const float*)d_in[6];
    const float* wk_b   = (const float*)d_in[7];
    const float* wv_w   = (const float*)d_in[8];
    const float* wv_b   = (const float*)d_in[9];
    const float* qn_g   = (const float*)d_in[10];
    const float* qn_b   = (const float*)d_in[11];
    const float* kn_g   = (const float*)d_in[12];
    const float* kn_b   = (const float*)d_in[13];
    const float* conv_w = (const float*)d_in[14];
    const float* conv_b = (const float*)d_in[15];
    const float* temp   = (const float*)d_in[16];

    float* out  = (float*)d_out;                          // (B,N,192)
    float* attn = out + (size_t)B_ * N_ * C_;             // (B,N,64)

    float* ws_vg = (float*)d_ws;                          // B*M*C = 98304 f
    float* ws_k  = ws_vg + B_ * M_ * C_;                  // 8192 f

    k_prep_kernel<<<B_ * M_,        256, 0, stream>>>(dict, wv_w, wv_b, conv_w, conv_b,
                                                      wk_w, wk_b, kn_g, kn_b, ws_vg, ws_k);
    k_main_kernel<<<B_ * (N_ / M_), 256, 0, stream>>>(x, ws_k, ws_vg, wq_w, wq_b,
                                                      qn_g, qn_b, temp, out, attn);
}

// Round 8
// 338.996 us; speedup vs baseline: 1.1107x; 1.0223x over previous
//
#include <hip/hip_runtime.h>
#include <math.h>

#define B_   8
#define N_   16384
#define M_   64
#define C_   192
#define RC_  16

#define FMA4(acc, s, v) \
    acc.x = fmaf(s, v.x, acc.x); acc.y = fmaf(s, v.y, acc.y); \
    acc.z = fmaf(s, v.z, acc.z); acc.w = fmaf(s, v.w, acc.w)

// ---------------------------------------------------------------------------
// K_prep: fused  v = dict@wv+b  ->  depthwise conv3x1 + GELU  -> ws_vg
//         and    k = l2norm(LN(dict@wk+b))                    -> ws_k
// (unchanged — verified correct)
// ---------------------------------------------------------------------------
__global__ __launch_bounds__(256) void k_prep_kernel(
    const float* __restrict__ dict,
    const float* __restrict__ wv_w, const float* __restrict__ wv_b,
    const float* __restrict__ conv_w, const float* __restrict__ conv_b,
    const float* __restrict__ wk_w, const float* __restrict__ wk_b,
    const float* __restrict__ kn_g, const float* __restrict__ kn_b,
    float* __restrict__ ws_vg, float* __restrict__ ws_k)
{
    const int b   = blockIdx.x >> 6;
    const int m   = blockIdx.x & 63;
    const int tid = threadIdx.x;
    const float* d0 = dict + (b * M_ + m) * C_;

    if (tid < 192) {
        const int c = tid;
        const bool hm = (m > 0), hp = (m < M_ - 1);
        const float* dm = hm ? d0 - C_ : d0;
        const float* dp = hp ? d0 + C_ : d0;
        float am = 0.f, ac = 0.f, ap = 0.f;
        #pragma unroll 4
        for (int d = 0; d < C_; ++d) {
            const float w = wv_w[d * C_ + c];
            am = fmaf(dm[d], w, am);
            ac = fmaf(d0[d], w, ac);
            ap = fmaf(dp[d], w, ap);
        }
        const float bia = wv_b[c];
        const float up = hm ? (am + bia) : 0.f;
        const float ct = ac + bia;
        const float dn = hp ? (ap + bia) : 0.f;
        float t = conv_b[c];
        t = fmaf(up, conv_w[c*9 + 1], t);
        t = fmaf(ct, conv_w[c*9 + 4], t);
        t = fmaf(dn, conv_w[c*9 + 7], t);
        ws_vg[(b * M_ + m) * C_ + c] = 0.5f * t * (1.0f + erff(t * 0.70710678118654752f));
    } else if (tid < 196) {
        const int j4 = tid - 192;
        const int c0 = j4 * 4;
        float a0 = wk_b[c0+0], a1 = wk_b[c0+1], a2 = wk_b[c0+2], a3 = wk_b[c0+3];
        #pragma unroll 4
        for (int d4 = 0; d4 < C_/4; ++d4) {
            const float4 xv = ((const float4*)d0)[d4];
            const float4 w0 = *(const float4*)&wk_w[(d4*4+0)*RC_ + c0];
            const float4 w1 = *(const float4*)&wk_w[(d4*4+1)*RC_ + c0];
            const float4 w2 = *(const float4*)&wk_w[(d4*4+2)*RC_ + c0];
            const float4 w3 = *(const float4*)&wk_w[(d4*4+3)*RC_ + c0];
            a0 = fmaf(xv.x, w0.x, a0); a1 = fmaf(xv.x, w0.y, a1); a2 = fmaf(xv.x, w0.z, a2); a3 = fmaf(xv.x, w0.w, a3);
            a0 = fmaf(xv.y, w1.x, a0); a1 = fmaf(xv.y, w1.y, a1); a2 = fmaf(xv.y, w1.z, a2); a3 = fmaf(xv.y, w1.w, a3);
            a0 = fmaf(xv.z, w2.x, a0); a1 = fmaf(xv.z, w2.y, a1); a2 = fmaf(xv.z, w2.z, a2); a3 = fmaf(xv.z, w2.w, a3);
            a0 = fmaf(xv.w, w3.x, a0); a1 = fmaf(xv.w, w3.y, a1); a2 = fmaf(xv.w, w3.z, a2); a3 = fmaf(xv.w, w3.w, a3);
        }
        float s  = a0 + a1 + a2 + a3;
        float ss = a0*a0 + a1*a1 + a2*a2 + a3*a3;
        s  += __shfl_xor(s, 1);  s  += __shfl_xor(s, 2);
        ss += __shfl_xor(ss, 1); ss += __shfl_xor(ss, 2);
        const float mu   = s * (1.0f/16.0f);
        const float var  = ss * (1.0f/16.0f) - mu*mu;
        const float rstd = rsqrtf(var + 1e-5f);
        const float4 g4 = *(const float4*)&kn_g[c0];
        const float4 b4 = *(const float4*)&kn_b[c0];
        const float y0 = (a0 - mu) * rstd * g4.x + b4.x;
        const float y1 = (a1 - mu) * rstd * g4.y + b4.y;
        const float y2 = (a2 - mu) * rstd * g4.z + b4.z;
        const float y3 = (a3 - mu) * rstd * g4.w + b4.w;
        float n2 = y0*y0 + y1*y1 + y2*y2 + y3*y3;
        n2 += __shfl_xor(n2, 1); n2 += __shfl_xor(n2, 2);
        const float inv = 1.0f / fmaxf(sqrtf(n2), 1e-12f);
        float4 o; o.x = y0*inv; o.y = y1*inv; o.z = y2*inv; o.w = y3*inv;
        *(float4*)&ws_k[(b * M_ + m) * RC_ + c0] = o;
    }
}

// ---------------------------------------------------------------------------
// K_main: 256 threads (4 waves), 64 rows/block, grid 2048.
//   LDS = vg(48K)+k(4K) = 52K -> 3 blocks/CU = 12 waves/CU (LDS-limited).
//   __launch_bounds__(256, 2): the ONLY bound that never spilled (r3).
//   Aggressive bounds (256,3)/(512,4) made the allocator spill ~48 regs to
//   scratch (+87..+144 MB HBM writes, r4/r6/r7). Spill tripwire: WRITE_SIZE
//   must equal 131 MB.
//   Staging: global->LDS at kernel TOP with short reg live-ranges (the T14
//   deferred-write held 48 VGPRs across phase (a) and was the spill victim).
//   (a) q proj + LN + l2norm   thread (r=tid>>2, j4); quad shfl stats
//   (b) softmax                thread (r,j4) owns m = 4*mm+j4; sc in regs
//   (c) out = attn @ vg        lane (rql,cq) = 4 rows x 12 ch tile;
//       attn[16wv+4rql+i][m] via in-wave shfl from lane 16rql+4i+(m&3),
//       static sc[m>>2] -> 4 shfl + 3 ds_read_b128 per m per wave.
//   ONE barrier in the whole kernel.
// ---------------------------------------------------------------------------
__global__ __launch_bounds__(256, 2) void k_main_kernel(
    const float* __restrict__ x, const float* __restrict__ ws_k,
    const float* __restrict__ ws_vg,
    const float* __restrict__ wq_w, const float* __restrict__ wq_b,
    const float* __restrict__ qn_g, const float* __restrict__ qn_b,
    const float* __restrict__ temp,
    float* __restrict__ out, float* __restrict__ attn_out)
{
    __shared__ float vg_s[M_ * C_];   // 48 KB
    __shared__ float k_s[M_ * RC_];   // 4 KB

    const int tid   = threadIdx.x;
    const int b     = blockIdx.x >> 8;
    const int n0    = (blockIdx.x & 255) * M_;
    const int lane  = tid & 63;
    const int lbase = lane & ~3;

    // ---- stage global->LDS NOW (short live ranges; no 48-reg hold) ----
    {
        const float4* vgb4 = (const float4*)(ws_vg + b * (M_ * C_));
        float4*       vgs4 = (float4*)vg_s;
        #pragma unroll
        for (int i = 0; i < 12; ++i)
            vgs4[tid + 256 * i] = vgb4[tid + 256 * i];
        ((float4*)k_s)[tid] = ((const float4*)(ws_k + b * (M_ * RC_)))[tid];
    }

    const int r  = tid >> 2;      // 0..63
    const int j4 = tid & 3;
    const int c0 = j4 * 4;

    // ---- phase (a): q projection + LN + l2norm ----
    const float* xr = x + (size_t)(b * N_ + n0 + r) * C_;
    float a0 = wq_b[c0+0], a1 = wq_b[c0+1], a2 = wq_b[c0+2], a3 = wq_b[c0+3];
    #pragma unroll 4
    for (int d4 = 0; d4 < C_/4; ++d4) {
        const float4 xv = ((const float4*)xr)[d4];
        const float4 w0 = *(const float4*)&wq_w[(d4*4+0)*RC_ + c0];
        const float4 w1 = *(const float4*)&wq_w[(d4*4+1)*RC_ + c0];
        const float4 w2 = *(const float4*)&wq_w[(d4*4+2)*RC_ + c0];
        const float4 w3 = *(const float4*)&wq_w[(d4*4+3)*RC_ + c0];
        a0 = fmaf(xv.x, w0.x, a0); a1 = fmaf(xv.x, w0.y, a1); a2 = fmaf(xv.x, w0.z, a2); a3 = fmaf(xv.x, w0.w, a3);
        a0 = fmaf(xv.y, w1.x, a0); a1 = fmaf(xv.y, w1.y, a1); a2 = fmaf(xv.y, w1.z, a2); a3 = fmaf(xv.y, w1.w, a3);
        a0 = fmaf(xv.z, w2.x, a0); a1 = fmaf(xv.z, w2.y, a1); a2 = fmaf(xv.z, w2.z, a2); a3 = fmaf(xv.z, w2.w, a3);
        a0 = fmaf(xv.w, w3.x, a0); a1 = fmaf(xv.w, w3.y, a1); a2 = fmaf(xv.w, w3.z, a2); a3 = fmaf(xv.w, w3.w, a3);
    }
    float4 q[4];
    {
        float s  = a0 + a1 + a2 + a3;
        float ss = a0*a0 + a1*a1 + a2*a2 + a3*a3;
        s  += __shfl_xor(s, 1);  s  += __shfl_xor(s, 2);
        ss += __shfl_xor(ss, 1); ss += __shfl_xor(ss, 2);
        const float mu   = s * (1.0f/16.0f);
        const float var  = ss * (1.0f/16.0f) - mu*mu;
        const float rstd = rsqrtf(var + 1e-5f);
        const float4 g4 = *(const float4*)&qn_g[c0];
        const float4 b4 = *(const float4*)&qn_b[c0];
        const float y0 = (a0 - mu) * rstd * g4.x + b4.x;
        const float y1 = (a1 - mu) * rstd * g4.y + b4.y;
        const float y2 = (a2 - mu) * rstd * g4.z + b4.z;
        const float y3 = (a3 - mu) * rstd * g4.w + b4.w;
        float n2 = y0*y0 + y1*y1 + y2*y2 + y3*y3;
        n2 += __shfl_xor(n2, 1); n2 += __shfl_xor(n2, 2);
        const float inv = 1.0f / fmaxf(sqrtf(n2), 1e-12f);
        float4 o; o.x = y0*inv; o.y = y1*inv; o.z = y2*inv; o.w = y3*inv;
        #pragma unroll
        for (int j = 0; j < 4; ++j) {
            q[j].x = __shfl(o.x, lbase + j);
            q[j].y = __shfl(o.y, lbase + j);
            q[j].z = __shfl(o.z, lbase + j);
            q[j].w = __shfl(o.w, lbase + j);
        }
    }
    const float tinv = 1.0f / fmaxf(temp[0], 0.5f);

    __syncthreads();   // staging (done long ago) + all waves ready

    // ---- phase (b): scores + softmax; thread owns m = 4*mm + j4 ----
    float sc[16];
    {
        #pragma unroll
        for (int mm = 0; mm < 16; ++mm) {
            const int m = mm*4 + j4;
            const float4 k0 = *(const float4*)&k_s[m*RC_ + 0];
            const float4 k1 = *(const float4*)&k_s[m*RC_ + 4];
            const float4 k2 = *(const float4*)&k_s[m*RC_ + 8];
            const float4 k3 = *(const float4*)&k_s[m*RC_ + 12];
            float d = q[0].x*k0.x;
            d = fmaf(q[0].y, k0.y, d); d = fmaf(q[0].z, k0.z, d); d = fmaf(q[0].w, k0.w, d);
            d = fmaf(q[1].x, k1.x, d); d = fmaf(q[1].y, k1.y, d); d = fmaf(q[1].z, k1.z, d); d = fmaf(q[1].w, k1.w, d);
            d = fmaf(q[2].x, k2.x, d); d = fmaf(q[2].y, k2.y, d); d = fmaf(q[2].z, k2.z, d); d = fmaf(q[2].w, k2.w, d);
            d = fmaf(q[3].x, k3.x, d); d = fmaf(q[3].y, k3.y, d); d = fmaf(q[3].z, k3.z, d); d = fmaf(q[3].w, k3.w, d);
            sc[mm] = d * tinv;
        }
        float mx = sc[0];
        #pragma unroll
        for (int mm = 1; mm < 16; ++mm) mx = fmaxf(mx, sc[mm]);
        mx = fmaxf(mx, __shfl_xor(mx, 1)); mx = fmaxf(mx, __shfl_xor(mx, 2));
        float es = 0.0f;
        #pragma unroll
        for (int mm = 0; mm < 16; ++mm) { sc[mm] = expf(sc[mm] - mx); es += sc[mm]; }
        es += __shfl_xor(es, 1); es += __shfl_xor(es, 2);
        const float einv = 1.0f / es;
        float* aw = attn_out + (size_t)(b * N_ + n0 + r) * M_;
        #pragma unroll
        for (int mm = 0; mm < 16; ++mm) {
            sc[mm] *= einv;                 // normalized attn stays in regs
            aw[mm*4 + j4] = sc[mm];
        }
    }
    // NO second barrier: attn exchange is intra-wave from here on.

    // ---- phase (c): out = attn @ vg; lane (rql,cq) = 4 rows x 12 channels. ----
    {
        const int w0lane = tid & 63;
        const int rql = w0lane >> 4;            // 0..3
        const int cq  = w0lane & 15;            // 0..15
        const int wv  = tid >> 6;               // wave id 0..3
        const int bl  = rql * 16;               // owner-lane base (i adds 4i)

        float4 ac0[3], ac1[3], ac2[3], ac3[3];
        #pragma unroll
        for (int t = 0; t < 3; ++t) {
            ac0[t] = make_float4(0.f,0.f,0.f,0.f);
            ac1[t] = make_float4(0.f,0.f,0.f,0.f);
            ac2[t] = make_float4(0.f,0.f,0.f,0.f);
            ac3[t] = make_float4(0.f,0.f,0.f,0.f);
        }
        #pragma unroll
        for (int m = 0; m < M_; ++m) {
            const float p0 = __shfl(sc[m >> 2], bl + 0  + (m & 3));
            const float p1 = __shfl(sc[m >> 2], bl + 4  + (m & 3));
            const float p2 = __shfl(sc[m >> 2], bl + 8  + (m & 3));
            const float p3 = __shfl(sc[m >> 2], bl + 12 + (m & 3));
            const float4* vr = (const float4*)(vg_s + m*C_ + cq*12);
            #pragma unroll
            for (int t = 0; t < 3; ++t) {
                const float4 v = vr[t];
                FMA4(ac0[t], p0, v);
                FMA4(ac1[t], p1, v);
                FMA4(ac2[t], p2, v);
                FMA4(ac3[t], p3, v);
            }
        }
        const int row0 = 16*wv + 4*rql;
        float* o0 = out + (size_t)(b * N_ + n0 + row0) * C_ + cq*12;
        #pragma unroll
        for (int t = 0; t < 3; ++t) {
            *(float4*)&o0[t*4]          = ac0[t];
            *(float4*)&o0[C_   + t*4]   = ac1[t];
            *(float4*)&o0[2*C_ + t*4]   = ac2[t];
            *(float4*)&o0[3*C_ + t*4]   = ac3[t];
        }
    }
}

// ---------------------------------------------------------------------------
extern "C" void kernel_launch(void* const* d_in, const int* in_sizes, int n_in,
                              void* d_out, int out_size, void* d_ws, size_t ws_size,
                              hipStream_t stream) {
    const float* x      = (const float*)d_in[0];
    const float* dict   = (const float*)d_in[1];
    const float* wq_w   = (const float*)d_in[4];
    const float* wq_b   = (const float*)d_in[5];
    const float* wk_w   = (const float*)d_in[6];
    const float* wk_b   = (const float*)d_in[7];
    const float* wv_w   = (const float*)d_in[8];
    const float* wv_b   = (const float*)d_in[9];
    const float* qn_g   = (const float*)d_in[10];
    const float* qn_b   = (const float*)d_in[11];
    const float* kn_g   = (const float*)d_in[12];
    const float* kn_b   = (const float*)d_in[13];
    const float* conv_w = (const float*)d_in[14];
    const float* conv_b = (const float*)d_in[15];
    const float* temp   = (const float*)d_in[16];

    float* out  = (float*)d_out;                          // (B,N,192)
    float* attn = out + (size_t)B_ * N_ * C_;             // (B,N,64)

    float* ws_vg = (float*)d_ws;                          // B*M*C = 98304 f
    float* ws_k  = ws_vg + B_ * M_ * C_;                  // 8192 f

    k_prep_kernel<<<B_ * M_,        256, 0, stream>>>(dict, wv_w, wv_b, conv_w, conv_b,
                                                      wk_w, wk_b, kn_g, kn_b, ws_vg, ws_k);
    k_main_kernel<<<B_ * (N_ / M_), 256, 0, stream>>>(x, ws_k, ws_vg, wq_w, wq_b,
                                                      qn_g, qn_b, temp, out, attn);
}